// Round 2
// baseline (126.688 us; speedup 1.0000x reference)
//
#include <hip/hip_runtime.h>

// One block = one (batch b, token-octet sg): tokens s = 8*sg .. 8*sg+7.
// Analytic collapse of the 8-wire circuit:
//   <Z_0> = prod_{j=1..7} cos(t_j+theta_j),  <Z_w> = prod_{j=0..w} cos(t_j+theta_j)
// (CNOT ring = basis permutation; product state probs are independent Bernoulli.)
// The scramble out.transpose(0,2,1,3).reshape(B,512,64) maps the 8 tokens of one
// octet to 8 complete rows r = 64*h + sg (col = 8*(s&7)+w), so the final GEMM
// with Wo fuses in-block.
__global__ __launch_bounds__(256)
void qattn_fused(const float* __restrict__ xg,
                 const float* __restrict__ wqg, const float* __restrict__ wkg,
                 const float* __restrict__ wvg, const float* __restrict__ wog,
                 const float* __restrict__ thg,
                 float* __restrict__ outg)
{
    __shared__ __align__(16) float sX[8 * 64];   // 8 token rows of x
    __shared__ float sQKV[3][8][64];             // [proj][tok][h*8+w]
    __shared__ __align__(16) float sScr[8][68];  // scrambled rows (pad to 68)

    const int tid  = threadIdx.x;
    const int lane = tid & 63;
    const int wg   = tid >> 6;       // wave id 0..3
    const int b    = blockIdx.x >> 6;
    const int sg   = blockIdx.x & 63;

    // stage x: 512 contiguous floats, coalesced
    {
        const float* xb = xg + (size_t)(b * 512 + sg * 8) * 64;
        sX[tid]       = xb[tid];
        sX[tid + 256] = xb[tid + 256];
    }
    const float thf = thg[lane & 7];
    __syncthreads();

    // ---- phase 1: wave wg in {0,1,2} computes projection wg for all 8 tokens.
    // q[t][e] = sum_k x[t][k] * W[e][k]; lane e reads W row e straight from
    // global (16 KB/matrix, L2-resident across the 1024 blocks).
    if (wg < 3) {
        const float* wm = (wg == 0) ? wqg : (wg == 1) ? wkg : wvg;
        const float4* wrow = (const float4*)(wm + lane * 64);  // 256B-aligned
        float acc[8] = {0.f, 0.f, 0.f, 0.f, 0.f, 0.f, 0.f, 0.f};
        #pragma unroll
        for (int kc = 0; kc < 16; ++kc) {
            const float4 w4 = wrow[kc];
            #pragma unroll
            for (int t = 0; t < 8; ++t) {
                const float4 xv = *(const float4*)&sX[t * 64 + kc * 4]; // broadcast
                acc[t] = fmaf(w4.x, xv.x, acc[t]);
                acc[t] = fmaf(w4.y, xv.y, acc[t]);
                acc[t] = fmaf(w4.z, xv.z, acc[t]);
                acc[t] = fmaf(w4.w, xv.w, acc[t]);
            }
        }
        const int j = lane & 7;   // wire index within head group
        #pragma unroll
        for (int t = 0; t < 8; ++t) {
            const float c = cosf(acc[t] + thf);      // cos(t_j + theta_j)
            float d = (j == 0) ? 1.f : c;            // exclude c0 from the scan
            float s;
            s = __shfl_up(d, 1); if (j >= 1) d *= s; // segmented inclusive
            s = __shfl_up(d, 2); if (j >= 2) d *= s; // product scan over 8
            s = __shfl_up(d, 4); if (j >= 4) d *= s;
            const float c0 = __shfl(c, lane & ~7);   // c at j=0
            const float pf = __shfl(d, lane | 7);    // prod c1..c7
            sQKV[wg][t][lane] = (j == 0) ? pf : c0 * d;
        }
    }
    __syncthreads();

    // ---- phase 2: per-token 8x8 head-mixing attention; 2 tokens per wave ----
    {
        const int i = lane >> 3, j = lane & 7;  // score element (i,j)
        #pragma unroll
        for (int u = 0; u < 2; ++u) {
            const int t = wg * 2 + u;
            float sc = 0.f;
            #pragma unroll
            for (int w = 0; w < 8; ++w)
                sc = fmaf(sQKV[0][t][i * 8 + w], sQKV[1][t][j * 8 + w], sc);
            sc *= 0.35355339059327373f;   // 1/sqrt(8)
            float m = sc;
            m = fmaxf(m, __shfl_xor(m, 1));
            m = fmaxf(m, __shfl_xor(m, 2));
            m = fmaxf(m, __shfl_xor(m, 4));
            const float ex = expf(sc - m);
            float sum = ex;
            sum += __shfl_xor(sum, 1);
            sum += __shfl_xor(sum, 2);
            sum += __shfl_xor(sum, 4);
            const float a = ex / sum;      // attn[t][i][j] held at lane i*8+j
            float o = 0.f;                 // out[t][i][w] with w = j here
            #pragma unroll
            for (int jj = 0; jj < 8; ++jj) {
                const float ajj = __shfl(a, (lane & ~7) + jj);  // attn[t][i][jj]
                o = fmaf(ajj, sQKV[2][t][jj * 8 + j], o);
            }
            sScr[i][t * 8 + j] = o;        // scrambled row h=i, col 8*(s&7)+w
        }
    }
    __syncthreads();

    // ---- phase 3: y[r] = scr_row @ Wo^T, 2 rows per wave; r = 64*h + sg ----
    {
        const float4* worow = (const float4*)(wog + lane * 64);
        #pragma unroll
        for (int u = 0; u < 2; ++u) {
            const int h = wg * 2 + u;
            float y = 0.f;
            #pragma unroll
            for (int kc = 0; kc < 16; ++kc) {
                const float4 w4 = worow[kc];
                const float4 sv = *(const float4*)&sScr[h][kc * 4]; // broadcast
                y = fmaf(w4.x, sv.x, y);
                y = fmaf(w4.y, sv.y, y);
                y = fmaf(w4.z, sv.z, y);
                y = fmaf(w4.w, sv.w, y);
            }
            outg[(size_t)(b * 512 + h * 64 + sg) * 64 + lane] = y;
        }
    }
}

extern "C" void kernel_launch(void* const* d_in, const int* in_sizes, int n_in,
                              void* d_out, int out_size, void* d_ws, size_t ws_size,
                              hipStream_t stream) {
    const float* x  = (const float*)d_in[0];
    const float* wq = (const float*)d_in[1];
    const float* wk = (const float*)d_in[2];
    const float* wv = (const float*)d_in[3];
    const float* wo = (const float*)d_in[4];
    const float* th = (const float*)d_in[5];
    float* out = (float*)d_out;
    // B=16, S=512 fixed by setup_inputs: 16 * (512/8) = 1024 blocks
    qattn_fused<<<dim3(1024), dim3(256), 0, stream>>>(x, wq, wk, wv, wo, th, out);
}

// Round 3
// 78.898 us; speedup vs baseline: 1.6057x; 1.6057x over previous
//
#include <hip/hip_runtime.h>

// Analytic collapse of the 8-wire circuit (verified R1, absmax 9.8e-4):
//   <Z_0> = prod_{j=1..7} cos(t_j+theta_j),  <Z_w> = prod_{j=0..w} cos(t_j+theta_j)
// One block = one (batch b, token-octet sg). Wave wg owns tokens 2wg, 2wg+1
// end-to-end (projections + attention), then heads 2wg, 2wg+1 of the fused
// output GEMM. W matrices staged once per block into LDS, row stride 68
// (minimal-conflict b128 reads). x / scrambled rows broadcast via readlane.

#define WS 68  // LDS row stride for 64-float W rows (68*4 B = 272 B, 16B-aligned)

typedef float f32;

__device__ __forceinline__ float rl(float v, int l) {
    return __int_as_float(__builtin_amdgcn_readlane(__float_as_int(v), l));
}

__device__ __forceinline__ float fsel(const float4& v, int cc) {
    return cc == 0 ? v.x : cc == 1 ? v.y : cc == 2 ? v.z : v.w;
}

// segmented (8-lane) product scan -> <Z_w>; j = lane&7 (validated in R1)
__device__ __forceinline__ float expect_z(float ang, int j, int lane) {
    const float c = cosf(ang);
    float d = (j == 0) ? 1.f : c;
    float s;
    s = __shfl_up(d, 1); if (j >= 1) d *= s;
    s = __shfl_up(d, 2); if (j >= 2) d *= s;
    s = __shfl_up(d, 4); if (j >= 4) d *= s;
    const float c0 = __shfl(c, lane & ~7);   // c at j=0
    const float pf = __shfl(d, lane | 7);    // prod c1..c7
    return (j == 0) ? pf : c0 * d;
}

__global__ __launch_bounds__(256)
void qattn_fused(const float* __restrict__ xg,
                 const float* __restrict__ wqg, const float* __restrict__ wkg,
                 const float* __restrict__ wvg, const float* __restrict__ wog,
                 const float* __restrict__ thg,
                 float* __restrict__ outg)
{
    __shared__ __align__(16) float sW[4][64 * WS];   // Wq,Wk,Wv,Wo  (69632 B)
    __shared__ float sP[4][3][2][64];                // wave-local q,k,v (6144 B)
    __shared__ float sScr[8][WS];                    // scrambled rows  (2176 B)

    const int tid  = threadIdx.x;
    const int lane = tid & 63;
    const int wg   = tid >> 6;
    const int b    = blockIdx.x >> 6;
    const int sg   = blockIdx.x & 63;
    const int t0   = wg * 2;

    // ---- stage all 4 W matrices, coalesced float4 global -> padded LDS ----
    {
        const float* gm[4] = {wqg, wkg, wvg, wog};
        #pragma unroll
        for (int m = 0; m < 4; ++m) {
            const float4* gv = (const float4*)gm[m];
            #pragma unroll
            for (int i = 0; i < 4; ++i) {
                const int g = tid + 256 * i;          // float4 index 0..1023
                const float4 v = gv[g];
                *(float4*)&sW[m][(g >> 4) * WS + (g & 15) * 4] = v;
            }
        }
    }
    // x rows for this wave's 2 tokens (coalesced, 256 B per load)
    const float* xb = xg + (size_t)(b * 512 + sg * 8 + t0) * 64;
    const float xr0 = xb[lane];
    const float xr1 = xb[64 + lane];
    const float thf = thg[lane & 7];
    __syncthreads();

    // ---- phase 1: q,k,v projections for tokens t0,t0+1 (lane = out elem e) ----
    float aq0 = 0.f, aq1 = 0.f, ak0 = 0.f, ak1 = 0.f, av0 = 0.f, av1 = 0.f;
    #pragma unroll 4
    for (int kc = 0; kc < 16; ++kc) {
        const float4 wq4 = *(const float4*)&sW[0][lane * WS + kc * 4];
        const float4 wk4 = *(const float4*)&sW[1][lane * WS + kc * 4];
        const float4 wv4 = *(const float4*)&sW[2][lane * WS + kc * 4];
        #pragma unroll
        for (int cc = 0; cc < 4; ++cc) {
            const int k = kc * 4 + cc;
            const float xa = rl(xr0, k);
            const float xc = rl(xr1, k);
            const float wq = fsel(wq4, cc), wk = fsel(wk4, cc), wv = fsel(wv4, cc);
            aq0 = fmaf(wq, xa, aq0); aq1 = fmaf(wq, xc, aq1);
            ak0 = fmaf(wk, xa, ak0); ak1 = fmaf(wk, xc, ak1);
            av0 = fmaf(wv, xa, av0); av1 = fmaf(wv, xc, av1);
        }
    }
    {
        const int j = lane & 7;
        sP[wg][0][0][lane] = expect_z(aq0 + thf, j, lane);
        sP[wg][0][1][lane] = expect_z(aq1 + thf, j, lane);
        sP[wg][1][0][lane] = expect_z(ak0 + thf, j, lane);
        sP[wg][1][1][lane] = expect_z(ak1 + thf, j, lane);
        sP[wg][2][0][lane] = expect_z(av0 + thf, j, lane);
        sP[wg][2][1][lane] = expect_z(av1 + thf, j, lane);
    }

    // ---- phase 2: per-token 8x8 head-mixing attention (wave-local, no barrier) ----
    {
        const int i = lane >> 3, j = lane & 7;
        #pragma unroll
        for (int u = 0; u < 2; ++u) {
            const int t = t0 + u;
            const float* q = sP[wg][0][u];
            const float* kk = sP[wg][1][u];
            const float* vv = sP[wg][2][u];
            float sc = 0.f;
            #pragma unroll
            for (int w = 0; w < 8; ++w)
                sc = fmaf(q[i * 8 + w], kk[j * 8 + w], sc);
            sc *= 0.35355339059327373f;   // 1/sqrt(8)
            float m = sc;
            m = fmaxf(m, __shfl_xor(m, 1));
            m = fmaxf(m, __shfl_xor(m, 2));
            m = fmaxf(m, __shfl_xor(m, 4));
            const float ex = expf(sc - m);
            float sum = ex;
            sum += __shfl_xor(sum, 1);
            sum += __shfl_xor(sum, 2);
            sum += __shfl_xor(sum, 4);
            const float a = ex / sum;      // attn[t][i][j] at lane i*8+j
            float o = 0.f;                 // out[t][i][w], w = j
            #pragma unroll
            for (int jj = 0; jj < 8; ++jj) {
                const float ajj = __shfl(a, (lane & ~7) + jj);
                o = fmaf(ajj, vv[jj * 8 + j], o);
            }
            sScr[i][t * 8 + j] = o;        // scrambled row h=i, col 8*(s&7)+w
        }
    }
    __syncthreads();

    // ---- phase 3: y[r] = scr_row @ Wo^T; wave handles heads 2wg, 2wg+1 ----
    {
        #pragma unroll
        for (int u = 0; u < 2; ++u) {
            const int h = t0 + u;
            const float scr = sScr[h][lane];   // lane k holds scr[h][k]
            float y = 0.f;
            #pragma unroll 4
            for (int kc = 0; kc < 16; ++kc) {
                const float4 w4 = *(const float4*)&sW[3][lane * WS + kc * 4];
                #pragma unroll
                for (int cc = 0; cc < 4; ++cc)
                    y = fmaf(fsel(w4, cc), rl(scr, kc * 4 + cc), y);
            }
            outg[(size_t)(b * 512 + h * 64 + sg) * 64 + lane] = y;
        }
    }
}

extern "C" void kernel_launch(void* const* d_in, const int* in_sizes, int n_in,
                              void* d_out, int out_size, void* d_ws, size_t ws_size,
                              hipStream_t stream) {
    const float* x  = (const float*)d_in[0];
    const float* wq = (const float*)d_in[1];
    const float* wk = (const float*)d_in[2];
    const float* wv = (const float*)d_in[3];
    const float* wo = (const float*)d_in[4];
    const float* th = (const float*)d_in[5];
    float* out = (float*)d_out;
    // B=16, S=512 fixed by setup_inputs: 16 * (512/8) = 1024 blocks
    qattn_fused<<<dim3(1024), dim3(256), 0, stream>>>(x, wq, wk, wv, wo, th, out);
}